// Round 6
// baseline (279.987 us; speedup 1.0000x reference)
//
#include <hip/hip_runtime.h>
#include <math.h>

#define NB 16
#define NS 32
#define NH 768
#define NE 200000
#define NT 200000
#define NR 500
#define NSTEPS 3
#define NWAYS 2

#define HSZ 2048      // frontier hash slots per (gen,b) -- keys shared across ways
#define AHSZ 4096     // accumulator hash slots (final, LDS)
#define BMW 6272      // bitmap u32 words per b (6250 used)
#define PCHUNK 25     // prop chunks per b

typedef unsigned int u32;

__device__ __forceinline__ int fhash(int e) { return (int)(((u32)e * 2654435761u) >> 21); } // 0..2047
__device__ __forceinline__ int ahash(int e) { return (int)(((u32)e * 2654435761u) >> 20); } // 0..4095

// ================= cq partials: disjoint 192x64 stepW slices, b batched =================
// grid: kc(4) x wt(6) x jc(12) = 288 blocks, 256 threads
__global__ __launch_bounds__(256) void cq_part_kernel(
    const float* __restrict__ qe, const float* __restrict__ stepW,
    float* __restrict__ part)
{
    int blk = blockIdx.x;              // kc*72 + wt*12 + jc
    int jc = blk % 12;
    int wt = (blk / 12) % 6;
    int kc = blk / 72;

    __shared__ float s_qe[192 * NB];   // [hh][b]
    __shared__ float s_part[2][1024];

    int tid = threadIdx.x;
    for (int i = tid; i < 192 * NB; i += 256) {
        int b = i / 192, hh = i % 192;
        s_qe[hh * NB + b] = qe[b * NH + kc * 192 + hh];
    }
    __syncthreads();

    int r = tid & 63, p = tid >> 6;
    const float* W = stepW + (size_t)wt * NH * NH + (size_t)(kc * 192) * NH + jc * 64 + r;
    float acc[NB];
#pragma unroll
    for (int b = 0; b < NB; ++b) acc[b] = 0.f;
#pragma unroll 2
    for (int hh = 0; hh < 48; ++hh) {
        int h = p * 48 + hh;
        float w = W[(size_t)h * NH];
        const float4* q4 = (const float4*)&s_qe[h * NB];
        float4 qa = q4[0], qb = q4[1], qc = q4[2], qd = q4[3];
        acc[0]  += w * qa.x; acc[1]  += w * qa.y; acc[2]  += w * qa.z; acc[3]  += w * qa.w;
        acc[4]  += w * qb.x; acc[5]  += w * qb.y; acc[6]  += w * qb.z; acc[7]  += w * qb.w;
        acc[8]  += w * qc.x; acc[9]  += w * qc.y; acc[10] += w * qc.z; acc[11] += w * qc.w;
        acc[12] += w * qd.x; acc[13] += w * qd.y; acc[14] += w * qd.z; acc[15] += w * qd.w;
    }
    if (p >= 2) {
#pragma unroll
        for (int b = 0; b < NB; ++b) s_part[p - 2][b * 64 + r] = acc[b];
    }
    __syncthreads();
    if (p < 2) {
#pragma unroll
        for (int b = 0; b < NB; ++b) s_part[p][b * 64 + r] += acc[b];
    }
    __syncthreads();
    for (int o = tid; o < 1024; o += 256) {
        int b = o >> 6, rr = o & 63;
        part[(((size_t)kc * 6 + wt) * NB + b) * NH + jc * 64 + rr] = s_part[0][o] + s_part[1][o];
    }
}

// ================= QWR[w,b] = qwh[b] @ relW[w]  (32 x 500, K=768) =================
// grid: w(2) x b(16) x rc(8) = 256 blocks, 256 threads
__global__ __launch_bounds__(256) void qwr_kernel(
    const float* __restrict__ qwh, const float* __restrict__ relW,
    float* __restrict__ qwr)
{
    int rc = blockIdx.x & 7;
    int b  = (blockIdx.x >> 3) & 15;
    int w  = blockIdx.x >> 7;

    __shared__ float s_q[128][36];     // [hh][s], padded stride 36 (16B-aligned rows)

    int tid = threadIdx.x;
    int lane = tid & 63, p = tid >> 6;
    int col = rc * 64 + lane;
    int cl = col < NR ? col : NR - 1;
    const float* Wcol = relW + (size_t)w * NH * NR + cl;

    float acc[8];
#pragma unroll
    for (int j = 0; j < 8; ++j) acc[j] = 0.f;

    for (int k0 = 0; k0 < NH; k0 += 128) {
        for (int i = tid; i < 32 * 128; i += 256) {
            int s = i >> 7, hh = i & 127;
            s_q[hh][s] = qwh[((size_t)b * NS + s) * NH + k0 + hh];
        }
        __syncthreads();
#pragma unroll 4
        for (int hh = 0; hh < 128; ++hh) {
            float wv = Wcol[(size_t)(k0 + hh) * NR];
            const float4* q4 = (const float4*)&s_q[hh][p * 8];
            float4 qa = q4[0], qb = q4[1];
            acc[0] += wv * qa.x; acc[1] += wv * qa.y; acc[2] += wv * qa.z; acc[3] += wv * qa.w;
            acc[4] += wv * qb.x; acc[5] += wv * qb.y; acc[6] += wv * qb.z; acc[7] += wv * qb.w;
        }
        __syncthreads();
    }
    if (col < NR) {
#pragma unroll
        for (int j = 0; j < 8; ++j)
            qwr[(((size_t)(w * NB + b)) * NS + (p * 8 + j)) * NR + col] = acc[j];
    }
}

// ===== attn+rel: reduce cq partials -> tanh -> logits -> softmax -> rel (+hop) =====
// grid: wt*NB + b (96 blocks)
__global__ __launch_bounds__(256) void attn_rel_kernel(
    const float* __restrict__ part, const float* __restrict__ stepB,
    const float* __restrict__ qwh, const float* __restrict__ mask,
    const float* __restrict__ qwr, const float* __restrict__ relB,
    const float* __restrict__ qe, const float* __restrict__ hopW,
    const float* __restrict__ hopB,
    float* __restrict__ rel, float* __restrict__ hop)
{
    int b = blockIdx.x % NB;
    int wt = blockIdx.x / NB;
    int w = wt / NSTEPS;
    int t = wt % NSTEPS;

    __shared__ float s_cq[NH];
    __shared__ float s_sm[NS];
    __shared__ float s_hl[4];

    int tid = threadIdx.x;

    // 1. cq = tanh(sum of 4 partials + bias)
    for (int j = tid; j < NH; j += 256) {
        float a = stepB[wt * NH + j];
#pragma unroll
        for (int kc = 0; kc < 4; ++kc)
            a += part[(((size_t)kc * 6 + wt) * NB + b) * NH + j];
        s_cq[j] = tanhf(a);
    }
    __syncthreads();

    // 2. logits: 8 threads per s
    {
        int s = tid >> 3, l = tid & 7;
        const float* row = qwh + ((size_t)b * NS + s) * NH;
        float a = 0.f;
        for (int h = l; h < NH; h += 8) a += s_cq[h] * row[h];
        a += __shfl_down(a, 4, 8);
        a += __shfl_down(a, 2, 8);
        a += __shfl_down(a, 1, 8);
        if (l == 0) s_sm[s] = a;
    }
    __syncthreads();

    // 3. softmax * mask, renorm — wave-parallel (lanes 0..31)
    if (tid < 64) {
        float lg = (tid < 32) ? s_sm[tid] : -1e30f;
        float m = lg;
        for (int off = 16; off; off >>= 1) m = fmaxf(m, __shfl_xor(m, off, 32));
        float ev = expf(lg - m);
        float sum = ev;
        for (int off = 16; off; off >>= 1) sum += __shfl_xor(sum, off, 32);
        float d = ev / sum * ((tid < 32) ? mask[b * NS + tid] : 0.f);
        float sum2 = d;
        for (int off = 16; off; off >>= 1) sum2 += __shfl_xor(sum2, off, 32);
        d = d / (sum2 + 1e-6f);
        if (tid < 32) s_sm[tid] = d;
    }
    __syncthreads();

    // 4. rel = sigmoid(q_dist @ QWR + relB)
    {
        const float* Q = qwr + ((size_t)(w * NB + b)) * NS * NR;
        for (int r = tid; r < NR; r += 256) {
            float a = relB[w * NR + r];
#pragma unroll 8
            for (int s = 0; s < NS; ++s) a += s_sm[s] * Q[(size_t)s * NR + r];
            rel[((size_t)wt * NB + b) * NR + r] = 1.f / (1.f + expf(-a));
        }
    }

    // 5. hop attention (t==0 blocks only; block-uniform branch)
    if (t == 0) {
        int lane = tid & 63, wv = tid >> 6;
        if (wv < 3) {
            float a = 0.f;
            for (int h = lane; h < NH; h += 64)
                a += qe[b * NH + h] * hopW[((size_t)w * NH + h) * NSTEPS + wv];
            for (int off = 32; off; off >>= 1) a += __shfl_down(a, off, 64);
            if (lane == 0) s_hl[wv] = a + hopB[w * NSTEPS + wv];
        }
        __syncthreads();
        if (tid == 0) {
            float mx = fmaxf(s_hl[0], fmaxf(s_hl[1], s_hl[2]));
            float e0 = expf(s_hl[0] - mx), e1 = expf(s_hl[1] - mx), e2 = expf(s_hl[2] - mx);
            float inv = 1.f / (e0 + e1 + e2);
            hop[(w * NB + b) * NSTEPS + 0] = e0 * inv;
            hop[(w * NB + b) * NSTEPS + 1] = e1 * inv;
            hop[(w * NB + b) * NSTEPS + 2] = e2 * inv;
        }
    }
}

// ================= gen0 frontier from one-hot heads =================
__global__ void head_kernel(const float* __restrict__ heads, int* __restrict__ keys0,
                            float* __restrict__ vals0, u32* __restrict__ bm0)
{
    size_t N4 = (size_t)NB * NE / 4;
    const float4* h4 = (const float4*)heads;
    for (size_t i = (size_t)blockIdx.x * blockDim.x + threadIdx.x; i < N4;
         i += (size_t)gridDim.x * blockDim.x) {
        float4 v = h4[i];
        float c[4] = { v.x, v.y, v.z, v.w };
#pragma unroll
        for (int k = 0; k < 4; ++k) {
            if (c[k] != 0.0f) {
                size_t idx = i * 4 + k;
                int b = (int)(idx / NE);
                int e = (int)(idx % NE);
                int s = fhash(e);
                keys0[(size_t)b * HSZ + s] = e + 1;
                vals0[(size_t)b * HSZ + s] = 1.0f;
                vals0[(size_t)(NB + b) * HSZ + s] = 1.0f;
                atomicOr(&bm0[(size_t)b * BMW + (e >> 5)], 1u << (e & 31));
            }
        }
    }
}

// ================= propagate gen t -> gen t+1 (both ways, shared keys) =================
// grid: b(16) x chunk(25) = 400 blocks
__global__ __launch_bounds__(256) void prop_kernel(
    const int* __restrict__ triples,
    const u32* __restrict__ bmIn, const int* __restrict__ keysIn, const float* __restrict__ valsIn,
    u32* __restrict__ bmOut, int* __restrict__ keysOut, float* __restrict__ valsOut,
    const float* __restrict__ rel, int t)
{
    __shared__ u32 s_bm[BMW];
    int b = blockIdx.x / PCHUNK;
    int c = blockIdx.x % PCHUNK;
    const u32* g = bmIn + (size_t)b * BMW;
    for (int k = threadIdx.x; k < BMW; k += 256) s_bm[k] = g[k];
    __syncthreads();

    const int*   kin  = keysIn  + (size_t)b * HSZ;
    const float* v0in = valsIn  + (size_t)b * HSZ;
    const float* v1in = valsIn  + (size_t)(NB + b) * HSZ;
    const float* r0 = rel + ((size_t)(0 * NSTEPS + t) * NB + b) * NR;
    const float* r1 = rel + ((size_t)(1 * NSTEPS + t) * NB + b) * NR;
    int*   kout  = keysOut + (size_t)b * HSZ;
    float* v0out = valsOut + (size_t)b * HSZ;
    float* v1out = valsOut + (size_t)(NB + b) * HSZ;
    u32*   bmo   = bmOut + (size_t)b * BMW;

    const int4* tp = (const int4*)(triples + (size_t)b * NT * 3);
    const int QPC = (NT / 4) / PCHUNK;     // 2000 quads per chunk
    int qend = (c + 1) * QPC;
    for (int q = c * QPC + threadIdx.x; q < qend; q += 256) {
        int4 x = tp[q * 3 + 0];
        int4 y = tp[q * 3 + 1];
        int4 z = tp[q * 3 + 2];
        int su[4] = { x.x, x.w, y.z, z.y };
        int re[4] = { x.y, y.x, y.w, z.z };
        int ob[4] = { x.z, y.y, z.x, z.w };
#pragma unroll
        for (int k = 0; k < 4; ++k) {
            int sub = su[k];
            if ((s_bm[sub >> 5] >> (sub & 31)) & 1u) {
                int s = fhash(sub);
                float v0 = 0.f, v1 = 0.f;
                bool found = false;
                for (int p = 0; p < HSZ; ++p) {
                    int kk = kin[s];
                    if (kk == 0) break;
                    if (kk == sub + 1) {
                        v0 = fminf(v0in[s], 1.0f);
                        v1 = fminf(v1in[s], 1.0f);
                        found = true;
                        break;
                    }
                    s = (s + 1) & (HSZ - 1);
                }
                if (found) {
                    float c0 = v0 * r0[re[k]];
                    float c1 = v1 * r1[re[k]];
                    int e = ob[k];
                    int s2 = fhash(e);
                    for (int p = 0; p < HSZ; ++p) {
                        int old = atomicCAS(&kout[s2], 0, e + 1);
                        if (old == 0 || old == e + 1) {
                            atomicAdd(&v0out[s2], c0);
                            atomicAdd(&v1out[s2], c1);
                            if (old == 0) atomicOr(&bmo[e >> 5], 1u << (e & 31));
                            break;
                        }
                        s2 = (s2 + 1) & (HSZ - 1);
                    }
                }
            }
        }
    }
}

// ================= final: hop-weighted accumulate gens 1..3, product of ways =================
__global__ __launch_bounds__(256) void final_kernel(
    const int* __restrict__ keysG, const float* __restrict__ valsG,
    const float* __restrict__ hop, float* __restrict__ out)
{
    __shared__ int s_k[AHSZ];
    __shared__ float s_v0[AHSZ];
    __shared__ float s_v1[AHSZ];
    int b = blockIdx.x;
    for (int i = threadIdx.x; i < AHSZ; i += 256) { s_k[i] = 0; s_v0[i] = 0.f; s_v1[i] = 0.f; }
    __syncthreads();
    for (int gen = 1; gen <= 3; ++gen) {
        const int* kg = keysG + ((size_t)gen * NB + b) * HSZ;
        const float* vg = valsG + (size_t)gen * NWAYS * NB * HSZ;
        const float* v0 = vg + (size_t)b * HSZ;
        const float* v1 = vg + (size_t)(NB + b) * HSZ;
        float h0 = hop[(0 * NB + b) * NSTEPS + (gen - 1)];
        float h1 = hop[(1 * NB + b) * NSTEPS + (gen - 1)];
        for (int i = threadIdx.x; i < HSZ; i += 256) {
            int key = kg[i];
            if (key == 0) continue;
            float a0 = h0 * fminf(v0[i], 1.0f);
            float a1 = h1 * fminf(v1[i], 1.0f);
            int s = ahash(key - 1);
            for (int p = 0; p < AHSZ; ++p) {
                int old = atomicCAS(&s_k[s], 0, key);
                if (old == 0 || old == key) {
                    atomicAdd(&s_v0[s], a0);
                    atomicAdd(&s_v1[s], a1);
                    break;
                }
                s = (s + 1) & (AHSZ - 1);
            }
        }
    }
    __syncthreads();
    for (int i = threadIdx.x; i < AHSZ; i += 256) {
        int key = s_k[i];
        if (key) out[(size_t)b * NE + (key - 1)] = s_v0[i] * s_v1[i];
    }
}

extern "C" void kernel_launch(void* const* d_in, const int* in_sizes, int n_in,
                              void* d_out, int out_size, void* d_ws, size_t ws_size,
                              hipStream_t stream)
{
    const float* heads  = (const float*)d_in[0];
    const float* qe     = (const float*)d_in[1];
    const float* qwh    = (const float*)d_in[2];
    const float* mask   = (const float*)d_in[3];
    const float* stepW  = (const float*)d_in[4];
    const float* stepB  = (const float*)d_in[5];
    const float* relW   = (const float*)d_in[6];
    const float* relB   = (const float*)d_in[7];
    const float* hopW   = (const float*)d_in[8];
    const float* hopB   = (const float*)d_in[9];
    const int*   triples = (const int*)d_in[10];
    float* out = (float*)d_out;

    // workspace: [keysG 4][valsG 4x2][bmG 4][rel][hop][part][qwr]
    int*   keysG = (int*)d_ws;                                   // 4*16*2048
    float* valsG = (float*)(keysG + 4 * NB * HSZ);               // 4*2*16*2048
    u32*   bmG   = (u32*)(valsG + 4 * NWAYS * NB * HSZ);         // 4*16*6272
    float* rel   = (float*)(bmG + 4 * (size_t)NB * BMW);         // 96*500
    float* hop   = rel + (size_t)NWAYS * NSTEPS * NB * NR;       // 96
    float* part  = hop + NWAYS * NB * NSTEPS;                    // 4*6*16*768
    float* qwr   = part + (size_t)4 * 6 * NB * NH;               // 2*16*32*500

    size_t zero_bytes = (char*)rel - (char*)d_ws;                // keys+vals+bm, ~3.1 MB
    hipMemsetAsync(d_ws, 0, zero_bytes, stream);
    hipMemsetAsync(d_out, 0, (size_t)NB * NE * sizeof(float), stream);

    cq_part_kernel<<<288, 256, 0, stream>>>(qe, stepW, part);
    qwr_kernel<<<256, 256, 0, stream>>>(qwh, relW, qwr);
    head_kernel<<<2048, 256, 0, stream>>>(heads, keysG, valsG, bmG);
    attn_rel_kernel<<<96, 256, 0, stream>>>(part, stepB, qwh, mask, qwr, relB,
                                            qe, hopW, hopB, rel, hop);

    for (int t = 0; t < NSTEPS; ++t) {
        prop_kernel<<<NB * PCHUNK, 256, 0, stream>>>(
            triples,
            bmG + (size_t)t * NB * BMW,
            keysG + (size_t)t * NB * HSZ,
            valsG + (size_t)t * NWAYS * NB * HSZ,
            bmG + (size_t)(t + 1) * NB * BMW,
            keysG + (size_t)(t + 1) * NB * HSZ,
            valsG + (size_t)(t + 1) * NWAYS * NB * HSZ,
            rel, t);
    }

    final_kernel<<<NB, 256, 0, stream>>>(keysG, valsG, hop, out);
}

// Round 7
// 224.468 us; speedup vs baseline: 1.2473x; 1.2473x over previous
//
#include <hip/hip_runtime.h>
#include <math.h>

#define NB 16
#define NS 32
#define NH 768
#define NE 200000
#define NT 200000
#define NR 500
#define NSTEPS 3
#define NWAYS 2

#define HSZ 2048      // frontier hash slots per (gen,b) -- keys shared across ways
#define AHSZ 4096     // accumulator hash slots (final, LDS)
#define BMW 6272      // bitmap u32 words per b (6250 used)
#define PCHUNK 25     // prop chunks per b

typedef unsigned int u32;

__device__ __forceinline__ int fhash(int e) { return (int)(((u32)e * 2654435761u) >> 21); } // 0..2047
__device__ __forceinline__ int ahash(int e) { return (int)(((u32)e * 2654435761u) >> 20); } // 0..4095

// ================= cq partials: LDS-staged stepW slice, b batched =================
// grid: kc(4) x wt(6) x jc(12) = 288 blocks, 256 threads (4 waves)
// block computes part[kc][wt][b 0..15][j = jc*64 + lane]
__global__ __launch_bounds__(256) void cq_part_kernel(
    const float* __restrict__ qe, const float* __restrict__ stepW,
    float* __restrict__ part)
{
    int blk = blockIdx.x;              // kc*72 + wt*12 + jc
    int jc = blk % 12;
    int wt = (blk / 12) % 6;
    int kc = blk / 72;

    __shared__ float s_w[192][68];     // W slice [hh][j], pad 68
    __shared__ float s_q[NB][196];     // qe slice [b][hh], pad 196

    int tid = threadIdx.x;
    int lane = tid & 63, wv = tid >> 6;

    // stage W: 192 rows x 64 cols = 3072 float4, 12 per thread
    {
        const float* Wbase = stepW + (size_t)wt * NH * NH + (size_t)(kc * 192) * NH + jc * 64;
#pragma unroll
        for (int u = 0; u < 12; ++u) {
            int f = tid + u * 256;
            int hh = f >> 4, c4 = (f & 15) * 4;
            float4 v = *(const float4*)(Wbase + (size_t)hh * NH + c4);
            *(float4*)&s_w[hh][c4] = v;
        }
    }
    // stage qe: 16 b x 192 = 768 float4, 3 per thread
    {
#pragma unroll
        for (int u = 0; u < 3; ++u) {
            int f = tid + u * 256;
            int b = f / 48, c4 = (f % 48) * 4;
            float4 v = *(const float4*)(qe + (size_t)b * NH + kc * 192 + c4);
            *(float4*)&s_q[b][c4] = v;
        }
    }
    __syncthreads();

    float acc[4] = {0.f, 0.f, 0.f, 0.f};
#pragma unroll 4
    for (int h4 = 0; h4 < 48; ++h4) {
        float w0 = s_w[h4 * 4 + 0][lane];
        float w1 = s_w[h4 * 4 + 1][lane];
        float w2 = s_w[h4 * 4 + 2][lane];
        float w3 = s_w[h4 * 4 + 3][lane];
#pragma unroll
        for (int i = 0; i < 4; ++i) {
            float4 q = *(const float4*)&s_q[wv * 4 + i][h4 * 4];
            acc[i] += w0 * q.x + w1 * q.y + w2 * q.z + w3 * q.w;
        }
    }
#pragma unroll
    for (int i = 0; i < 4; ++i) {
        int b = wv * 4 + i;
        part[(((size_t)kc * 6 + wt) * NB + b) * NH + jc * 64 + lane] = acc[i];
    }
}

// ================= QWR[w,b] = qwh[b] @ relW[w]  (32 x 500, K=768) =================
// grid: w(2) x b(16) x rc(8) = 256 blocks, 512 threads (8 waves)
// block computes qwr[w][b][s 0..31][col = rc*64 + lane]
__global__ __launch_bounds__(512) void qwr_kernel(
    const float* __restrict__ qwh, const float* __restrict__ relW,
    float* __restrict__ qwr)
{
    int rc = blockIdx.x & 7;
    int b  = (blockIdx.x >> 3) & 15;
    int w  = blockIdx.x >> 7;

    __shared__ float s_w[128][68];     // relW tile [hh][c], pad 68
    __shared__ float s_q[NS][132];     // qwh tile [s][hh], pad 132

    int tid = threadIdx.x;
    int lane = tid & 63, wv = tid >> 6;
    int col = rc * 64 + lane;

    float acc[4] = {0.f, 0.f, 0.f, 0.f};

    for (int k0 = 0; k0 < NH; k0 += 128) {
        // stage relW tile: 128 x 64 = 2048 float4, 4 per thread
        {
            const float* Wbase = relW + (size_t)w * NH * NR + (size_t)k0 * NR;
#pragma unroll
            for (int u = 0; u < 4; ++u) {
                int f = tid + u * 512;
                int hh = f >> 4;
                int c = rc * 64 + (f & 15) * 4;
                if (c > NR - 4) c = NR - 4;           // clamp (rc==7 tail); garbage cols discarded at store
                float4 v = *(const float4*)(Wbase + (size_t)hh * NR + c);
                *(float4*)&s_w[hh][(f & 15) * 4] = v;
            }
        }
        // stage qwh tile: 32 s x 128 = 1024 float4, 2 per thread
        {
#pragma unroll
            for (int u = 0; u < 2; ++u) {
                int f = tid + u * 512;
                int s = f >> 5, c4 = (f & 31) * 4;
                float4 v = *(const float4*)(qwh + ((size_t)b * NS + s) * NH + k0 + c4);
                *(float4*)&s_q[s][c4] = v;
            }
        }
        __syncthreads();

#pragma unroll 4
        for (int h4 = 0; h4 < 32; ++h4) {
            float w0 = s_w[h4 * 4 + 0][lane];
            float w1 = s_w[h4 * 4 + 1][lane];
            float w2 = s_w[h4 * 4 + 2][lane];
            float w3 = s_w[h4 * 4 + 3][lane];
#pragma unroll
            for (int i = 0; i < 4; ++i) {
                float4 q = *(const float4*)&s_q[wv * 4 + i][h4 * 4];
                acc[i] += w0 * q.x + w1 * q.y + w2 * q.z + w3 * q.w;
            }
        }
        __syncthreads();
    }

    if (col < NR) {
#pragma unroll
        for (int i = 0; i < 4; ++i)
            qwr[(((size_t)(w * NB + b)) * NS + (wv * 4 + i)) * NR + col] = acc[i];
    }
}

// ===== attn+rel: reduce cq partials -> tanh -> logits -> softmax -> rel (+hop) =====
// grid: wt*NB + b (96 blocks)
__global__ __launch_bounds__(256) void attn_rel_kernel(
    const float* __restrict__ part, const float* __restrict__ stepB,
    const float* __restrict__ qwh, const float* __restrict__ mask,
    const float* __restrict__ qwr, const float* __restrict__ relB,
    const float* __restrict__ qe, const float* __restrict__ hopW,
    const float* __restrict__ hopB,
    float* __restrict__ rel, float* __restrict__ hop)
{
    int b = blockIdx.x % NB;
    int wt = blockIdx.x / NB;
    int w = wt / NSTEPS;
    int t = wt % NSTEPS;

    __shared__ float s_cq[NH];
    __shared__ float s_sm[NS];
    __shared__ float s_hl[4];

    int tid = threadIdx.x;

    // 1. cq = tanh(sum of 4 partials + bias)
    for (int j = tid; j < NH; j += 256) {
        float a = stepB[wt * NH + j];
#pragma unroll
        for (int kc = 0; kc < 4; ++kc)
            a += part[(((size_t)kc * 6 + wt) * NB + b) * NH + j];
        s_cq[j] = tanhf(a);
    }
    __syncthreads();

    // 2. logits: 8 threads per s
    {
        int s = tid >> 3, l = tid & 7;
        const float* row = qwh + ((size_t)b * NS + s) * NH;
        float a = 0.f;
        for (int h = l; h < NH; h += 8) a += s_cq[h] * row[h];
        a += __shfl_down(a, 4, 8);
        a += __shfl_down(a, 2, 8);
        a += __shfl_down(a, 1, 8);
        if (l == 0) s_sm[s] = a;
    }
    __syncthreads();

    // 3. softmax * mask, renorm — wave-parallel (lanes 0..31)
    if (tid < 64) {
        float lg = (tid < 32) ? s_sm[tid] : -1e30f;
        float m = lg;
        for (int off = 16; off; off >>= 1) m = fmaxf(m, __shfl_xor(m, off, 32));
        float ev = expf(lg - m);
        float sum = ev;
        for (int off = 16; off; off >>= 1) sum += __shfl_xor(sum, off, 32);
        float d = ev / sum * ((tid < 32) ? mask[b * NS + tid] : 0.f);
        float sum2 = d;
        for (int off = 16; off; off >>= 1) sum2 += __shfl_xor(sum2, off, 32);
        d = d / (sum2 + 1e-6f);
        if (tid < 32) s_sm[tid] = d;
    }
    __syncthreads();

    // 4. rel = sigmoid(q_dist @ QWR + relB)
    {
        const float* Q = qwr + ((size_t)(w * NB + b)) * NS * NR;
        for (int r = tid; r < NR; r += 256) {
            float a = relB[w * NR + r];
#pragma unroll 8
            for (int s = 0; s < NS; ++s) a += s_sm[s] * Q[(size_t)s * NR + r];
            rel[((size_t)wt * NB + b) * NR + r] = 1.f / (1.f + expf(-a));
        }
    }

    // 5. hop attention (t==0 blocks only; block-uniform branch)
    if (t == 0) {
        int lane = tid & 63, wv = tid >> 6;
        if (wv < 3) {
            float a = 0.f;
            for (int h = lane; h < NH; h += 64)
                a += qe[b * NH + h] * hopW[((size_t)w * NH + h) * NSTEPS + wv];
            for (int off = 32; off; off >>= 1) a += __shfl_down(a, off, 64);
            if (lane == 0) s_hl[wv] = a + hopB[w * NSTEPS + wv];
        }
        __syncthreads();
        if (tid == 0) {
            float mx = fmaxf(s_hl[0], fmaxf(s_hl[1], s_hl[2]));
            float e0 = expf(s_hl[0] - mx), e1 = expf(s_hl[1] - mx), e2 = expf(s_hl[2] - mx);
            float inv = 1.f / (e0 + e1 + e2);
            hop[(w * NB + b) * NSTEPS + 0] = e0 * inv;
            hop[(w * NB + b) * NSTEPS + 1] = e1 * inv;
            hop[(w * NB + b) * NSTEPS + 2] = e2 * inv;
        }
    }
}

// ================= gen0 frontier from one-hot heads =================
__global__ void head_kernel(const float* __restrict__ heads, int* __restrict__ keys0,
                            float* __restrict__ vals0, u32* __restrict__ bm0)
{
    size_t N4 = (size_t)NB * NE / 4;
    const float4* h4 = (const float4*)heads;
    for (size_t i = (size_t)blockIdx.x * blockDim.x + threadIdx.x; i < N4;
         i += (size_t)gridDim.x * blockDim.x) {
        float4 v = h4[i];
        float c[4] = { v.x, v.y, v.z, v.w };
#pragma unroll
        for (int k = 0; k < 4; ++k) {
            if (c[k] != 0.0f) {
                size_t idx = i * 4 + k;
                int b = (int)(idx / NE);
                int e = (int)(idx % NE);
                int s = fhash(e);
                keys0[(size_t)b * HSZ + s] = e + 1;
                vals0[(size_t)b * HSZ + s] = 1.0f;
                vals0[(size_t)(NB + b) * HSZ + s] = 1.0f;
                atomicOr(&bm0[(size_t)b * BMW + (e >> 5)], 1u << (e & 31));
            }
        }
    }
}

// ================= propagate gen t -> gen t+1 (both ways, shared keys) =================
// grid: b(16) x chunk(25) = 400 blocks
__global__ __launch_bounds__(256) void prop_kernel(
    const int* __restrict__ triples,
    const u32* __restrict__ bmIn, const int* __restrict__ keysIn, const float* __restrict__ valsIn,
    u32* __restrict__ bmOut, int* __restrict__ keysOut, float* __restrict__ valsOut,
    const float* __restrict__ rel, int t)
{
    __shared__ u32 s_bm[BMW];
    int b = blockIdx.x / PCHUNK;
    int c = blockIdx.x % PCHUNK;
    const u32* g = bmIn + (size_t)b * BMW;
    for (int k = threadIdx.x; k < BMW; k += 256) s_bm[k] = g[k];
    __syncthreads();

    const int*   kin  = keysIn  + (size_t)b * HSZ;
    const float* v0in = valsIn  + (size_t)b * HSZ;
    const float* v1in = valsIn  + (size_t)(NB + b) * HSZ;
    const float* r0 = rel + ((size_t)(0 * NSTEPS + t) * NB + b) * NR;
    const float* r1 = rel + ((size_t)(1 * NSTEPS + t) * NB + b) * NR;
    int*   kout  = keysOut + (size_t)b * HSZ;
    float* v0out = valsOut + (size_t)b * HSZ;
    float* v1out = valsOut + (size_t)(NB + b) * HSZ;
    u32*   bmo   = bmOut + (size_t)b * BMW;

    const int4* tp = (const int4*)(triples + (size_t)b * NT * 3);
    const int QPC = (NT / 4) / PCHUNK;     // 2000 quads per chunk
    int qend = (c + 1) * QPC;
    for (int q = c * QPC + threadIdx.x; q < qend; q += 256) {
        int4 x = tp[q * 3 + 0];
        int4 y = tp[q * 3 + 1];
        int4 z = tp[q * 3 + 2];
        int su[4] = { x.x, x.w, y.z, z.y };
        int re[4] = { x.y, y.x, y.w, z.z };
        int ob[4] = { x.z, y.y, z.x, z.w };
#pragma unroll
        for (int k = 0; k < 4; ++k) {
            int sub = su[k];
            if ((s_bm[sub >> 5] >> (sub & 31)) & 1u) {
                int s = fhash(sub);
                float v0 = 0.f, v1 = 0.f;
                bool found = false;
                for (int p = 0; p < HSZ; ++p) {
                    int kk = kin[s];
                    if (kk == 0) break;
                    if (kk == sub + 1) {
                        v0 = fminf(v0in[s], 1.0f);
                        v1 = fminf(v1in[s], 1.0f);
                        found = true;
                        break;
                    }
                    s = (s + 1) & (HSZ - 1);
                }
                if (found) {
                    float c0 = v0 * r0[re[k]];
                    float c1 = v1 * r1[re[k]];
                    int e = ob[k];
                    int s2 = fhash(e);
                    for (int p = 0; p < HSZ; ++p) {
                        int old = atomicCAS(&kout[s2], 0, e + 1);
                        if (old == 0 || old == e + 1) {
                            atomicAdd(&v0out[s2], c0);
                            atomicAdd(&v1out[s2], c1);
                            if (old == 0) atomicOr(&bmo[e >> 5], 1u << (e & 31));
                            break;
                        }
                        s2 = (s2 + 1) & (HSZ - 1);
                    }
                }
            }
        }
    }
}

// ================= final: hop-weighted accumulate gens 1..3, product of ways =================
__global__ __launch_bounds__(256) void final_kernel(
    const int* __restrict__ keysG, const float* __restrict__ valsG,
    const float* __restrict__ hop, float* __restrict__ out)
{
    __shared__ int s_k[AHSZ];
    __shared__ float s_v0[AHSZ];
    __shared__ float s_v1[AHSZ];
    int b = blockIdx.x;
    for (int i = threadIdx.x; i < AHSZ; i += 256) { s_k[i] = 0; s_v0[i] = 0.f; s_v1[i] = 0.f; }
    __syncthreads();
    for (int gen = 1; gen <= 3; ++gen) {
        const int* kg = keysG + ((size_t)gen * NB + b) * HSZ;
        const float* vg = valsG + (size_t)gen * NWAYS * NB * HSZ;
        const float* v0 = vg + (size_t)b * HSZ;
        const float* v1 = vg + (size_t)(NB + b) * HSZ;
        float h0 = hop[(0 * NB + b) * NSTEPS + (gen - 1)];
        float h1 = hop[(1 * NB + b) * NSTEPS + (gen - 1)];
        for (int i = threadIdx.x; i < HSZ; i += 256) {
            int key = kg[i];
            if (key == 0) continue;
            float a0 = h0 * fminf(v0[i], 1.0f);
            float a1 = h1 * fminf(v1[i], 1.0f);
            int s = ahash(key - 1);
            for (int p = 0; p < AHSZ; ++p) {
                int old = atomicCAS(&s_k[s], 0, key);
                if (old == 0 || old == key) {
                    atomicAdd(&s_v0[s], a0);
                    atomicAdd(&s_v1[s], a1);
                    break;
                }
                s = (s + 1) & (AHSZ - 1);
            }
        }
    }
    __syncthreads();
    for (int i = threadIdx.x; i < AHSZ; i += 256) {
        int key = s_k[i];
        if (key) out[(size_t)b * NE + (key - 1)] = s_v0[i] * s_v1[i];
    }
}

extern "C" void kernel_launch(void* const* d_in, const int* in_sizes, int n_in,
                              void* d_out, int out_size, void* d_ws, size_t ws_size,
                              hipStream_t stream)
{
    const float* heads  = (const float*)d_in[0];
    const float* qe     = (const float*)d_in[1];
    const float* qwh    = (const float*)d_in[2];
    const float* mask   = (const float*)d_in[3];
    const float* stepW  = (const float*)d_in[4];
    const float* stepB  = (const float*)d_in[5];
    const float* relW   = (const float*)d_in[6];
    const float* relB   = (const float*)d_in[7];
    const float* hopW   = (const float*)d_in[8];
    const float* hopB   = (const float*)d_in[9];
    const int*   triples = (const int*)d_in[10];
    float* out = (float*)d_out;

    // workspace: [keysG 4][valsG 4x2][bmG 4][rel][hop][part][qwr]
    int*   keysG = (int*)d_ws;                                   // 4*16*2048
    float* valsG = (float*)(keysG + 4 * NB * HSZ);               // 4*2*16*2048
    u32*   bmG   = (u32*)(valsG + 4 * NWAYS * NB * HSZ);         // 4*16*6272
    float* rel   = (float*)(bmG + 4 * (size_t)NB * BMW);         // 96*500
    float* hop   = rel + (size_t)NWAYS * NSTEPS * NB * NR;       // 96
    float* part  = hop + NWAYS * NB * NSTEPS;                    // 4*6*16*768
    float* qwr   = part + (size_t)4 * 6 * NB * NH;               // 2*16*32*500

    size_t zero_bytes = (char*)rel - (char*)d_ws;                // keys+vals+bm, ~3.1 MB
    hipMemsetAsync(d_ws, 0, zero_bytes, stream);
    hipMemsetAsync(d_out, 0, (size_t)NB * NE * sizeof(float), stream);

    cq_part_kernel<<<288, 256, 0, stream>>>(qe, stepW, part);
    qwr_kernel<<<256, 512, 0, stream>>>(qwh, relW, qwr);
    head_kernel<<<2048, 256, 0, stream>>>(heads, keysG, valsG, bmG);
    attn_rel_kernel<<<96, 256, 0, stream>>>(part, stepB, qwh, mask, qwr, relB,
                                            qe, hopW, hopB, rel, hop);

    for (int t = 0; t < NSTEPS; ++t) {
        prop_kernel<<<NB * PCHUNK, 256, 0, stream>>>(
            triples,
            bmG + (size_t)t * NB * BMW,
            keysG + (size_t)t * NB * HSZ,
            valsG + (size_t)t * NWAYS * NB * HSZ,
            bmG + (size_t)(t + 1) * NB * BMW,
            keysG + (size_t)(t + 1) * NB * HSZ,
            valsG + (size_t)(t + 1) * NWAYS * NB * HSZ,
            rel, t);
    }

    final_kernel<<<NB, 256, 0, stream>>>(keysG, valsG, hop, out);
}

// Round 9
// 211.393 us; speedup vs baseline: 1.3245x; 1.0619x over previous
//
#include <hip/hip_runtime.h>
#include <math.h>

#define NB 16
#define NS 32
#define NH 768
#define NE 200000
#define NT 200000
#define NR 500
#define NSTEPS 3
#define NWAYS 2

#define HSZ 2048      // frontier hash slots per (gen,b) -- keys shared across ways
#define AHSZ 4096     // accumulator hash slots (final, LDS)
#define BMW 6272      // bitmap u32 words per b (6250 used)
#define PCHUNK 40     // prop chunks per b (QPC = 1250)

typedef unsigned int u32;

__device__ __forceinline__ int fhash(int e) { return (int)(((u32)e * 2654435761u) >> 21); } // 0..2047
__device__ __forceinline__ int ahash(int e) { return (int)(((u32)e * 2654435761u) >> 20); } // 0..4095

// ================= cq partials: LDS-staged stepW slice, b batched =================
// grid: kc(4) x wt(6) x jc(12) = 288 blocks, 256 threads (4 waves)
__global__ __launch_bounds__(256) void cq_part_kernel(
    const float* __restrict__ qe, const float* __restrict__ stepW,
    float* __restrict__ part)
{
    int blk = blockIdx.x;              // kc*72 + wt*12 + jc
    int jc = blk % 12;
    int wt = (blk / 12) % 6;
    int kc = blk / 72;

    __shared__ float s_w[192][68];     // W slice [hh][j], pad 68
    __shared__ float s_q[NB][196];     // qe slice [b][hh], pad 196

    int tid = threadIdx.x;
    int lane = tid & 63, wv = tid >> 6;

    // stage W: 192 rows x 64 cols = 3072 float4, 12 per thread
    {
        const float* Wbase = stepW + (size_t)wt * NH * NH + (size_t)(kc * 192) * NH + jc * 64;
#pragma unroll
        for (int u = 0; u < 12; ++u) {
            int f = tid + u * 256;
            int hh = f >> 4, c4 = (f & 15) * 4;
            float4 v = *(const float4*)(Wbase + (size_t)hh * NH + c4);
            *(float4*)&s_w[hh][c4] = v;
        }
    }
    // stage qe: 16 b x 192 = 768 float4, 3 per thread
    {
#pragma unroll
        for (int u = 0; u < 3; ++u) {
            int f = tid + u * 256;
            int b = f / 48, c4 = (f % 48) * 4;
            float4 v = *(const float4*)(qe + (size_t)b * NH + kc * 192 + c4);
            *(float4*)&s_q[b][c4] = v;
        }
    }
    __syncthreads();

    float acc[4] = {0.f, 0.f, 0.f, 0.f};
#pragma unroll 4
    for (int h4 = 0; h4 < 48; ++h4) {
        float w0 = s_w[h4 * 4 + 0][lane];
        float w1 = s_w[h4 * 4 + 1][lane];
        float w2 = s_w[h4 * 4 + 2][lane];
        float w3 = s_w[h4 * 4 + 3][lane];
#pragma unroll
        for (int i = 0; i < 4; ++i) {
            float4 q = *(const float4*)&s_q[wv * 4 + i][h4 * 4];
            acc[i] += w0 * q.x + w1 * q.y + w2 * q.z + w3 * q.w;
        }
    }
#pragma unroll
    for (int i = 0; i < 4; ++i) {
        int b = wv * 4 + i;
        part[(((size_t)kc * 6 + wt) * NB + b) * NH + jc * 64 + lane] = acc[i];
    }
}

// ===== attn: reduce cq partials -> tanh -> logits -> softmax -> ctx =====
// grid: wt*NB + b (96 blocks)
__global__ __launch_bounds__(256) void attn_kernel(
    const float* __restrict__ part, const float* __restrict__ stepB,
    const float* __restrict__ qwh, const float* __restrict__ mask,
    float* __restrict__ ctx)
{
    int b = blockIdx.x % NB;
    int wt = blockIdx.x / NB;

    __shared__ float s_cq[NH];
    __shared__ float s_sm[NS];

    int tid = threadIdx.x;

    // 1. cq = tanh(sum of 4 partials + bias)
    for (int j = tid; j < NH; j += 256) {
        float a = stepB[wt * NH + j];
#pragma unroll
        for (int kc = 0; kc < 4; ++kc)
            a += part[(((size_t)kc * 6 + wt) * NB + b) * NH + j];
        s_cq[j] = tanhf(a);
    }
    __syncthreads();

    // 2. logits: 8 threads per s
    {
        int s = tid >> 3, l = tid & 7;
        const float* row = qwh + ((size_t)b * NS + s) * NH;
        float a = 0.f;
        for (int h = l; h < NH; h += 8) a += s_cq[h] * row[h];
        a += __shfl_down(a, 4, 8);
        a += __shfl_down(a, 2, 8);
        a += __shfl_down(a, 1, 8);
        if (l == 0) s_sm[s] = a;
    }
    __syncthreads();

    // 3. softmax * mask, renorm — wave-parallel (lanes 0..31)
    if (tid < 64) {
        float lg = (tid < 32) ? s_sm[tid] : -1e30f;
        float m = lg;
        for (int off = 16; off; off >>= 1) m = fmaxf(m, __shfl_xor(m, off, 32));
        float ev = expf(lg - m);
        float sum = ev;
        for (int off = 16; off; off >>= 1) sum += __shfl_xor(sum, off, 32);
        float d = ev / sum * ((tid < 32) ? mask[b * NS + tid] : 0.f);
        float sum2 = d;
        for (int off = 16; off; off >>= 1) sum2 += __shfl_xor(sum2, off, 32);
        d = d / (sum2 + 1e-6f);
        if (tid < 32) s_sm[tid] = d;
    }
    __syncthreads();

    // 4. ctx = q_dist @ qwh
    for (int h = tid; h < NH; h += 256) {
        const float* col = qwh + (size_t)b * NS * NH + h;
        float c = 0.f;
#pragma unroll 8
        for (int s = 0; s < NS; ++s) c += s_sm[s] * col[s * NH];
        ctx[((size_t)wt * NB + b) * NH + h] = c;
    }
}

// ================= rel partials: disjoint relW 64k x 64c slices =================
// grid: kc(12) x w(2) x rc(8) = 192 blocks, 256 threads
__global__ __launch_bounds__(256) void rel_part_kernel(
    const float* __restrict__ ctx, const float* __restrict__ relW,
    float* __restrict__ part_r)
{
    int blk = blockIdx.x;              // kc*16 + w*8 + rc
    int rc = blk & 7;
    int w  = (blk >> 3) & 1;
    int kc = blk >> 4;

    __shared__ float s_ctx[48][68];    // [tb][kk]

    int tid = threadIdx.x;
    int lane = tid & 63, wv = tid >> 6;

    // stage ctx: 48 tb x 64 k = 768 float4; 3 per thread
#pragma unroll
    for (int u = 0; u < 3; ++u) {
        int f = tid + u * 256;
        int tb = f >> 4, c4 = (f & 15) * 4;
        int t = tb >> 4, b = tb & 15;
        float4 v = *(const float4*)(ctx + ((size_t)(w * 3 + t) * NB + b) * NH + kc * 64 + c4);
        *(float4*)&s_ctx[tb][c4] = v;
    }
    __syncthreads();

    int col = rc * 64 + lane;
    int colc = col < NR ? col : NR - 1;
    const float* Wb = relW + (size_t)w * NH * NR + (size_t)(kc * 64) * NR + colc;

    float acc[12];
#pragma unroll
    for (int i = 0; i < 12; ++i) acc[i] = 0.f;

#pragma unroll 4
    for (int h4 = 0; h4 < 16; ++h4) {
        float w0 = Wb[(size_t)(h4 * 4 + 0) * NR];
        float w1 = Wb[(size_t)(h4 * 4 + 1) * NR];
        float w2 = Wb[(size_t)(h4 * 4 + 2) * NR];
        float w3 = Wb[(size_t)(h4 * 4 + 3) * NR];
#pragma unroll
        for (int i = 0; i < 12; ++i) {
            float4 c = *(const float4*)&s_ctx[wv * 12 + i][h4 * 4];
            acc[i] += w0 * c.x + w1 * c.y + w2 * c.z + w3 * c.w;
        }
    }
    if (col < NR) {
#pragma unroll
        for (int i = 0; i < 12; ++i) {
            int tb = wv * 12 + i;
            int t = tb >> 4, b = tb & 15;
            part_r[(((size_t)kc * 6 + (w * 3 + t)) * NB + b) * NR + col] = acc[i];
        }
    }
}

// ================= rel reduce: sum 12 partials + bias, sigmoid =================
// grid: 96 blocks (wt*NB+b), 256 threads
__global__ void rel_reduce_kernel(const float* __restrict__ part_r,
                                  const float* __restrict__ relB,
                                  float* __restrict__ rel)
{
    int b = blockIdx.x % NB;
    int wt = blockIdx.x / NB;
    int w = wt / NSTEPS;
    for (int r = threadIdx.x; r < NR; r += 256) {
        float a = relB[w * NR + r];
#pragma unroll
        for (int kc = 0; kc < 12; ++kc)
            a += part_r[(((size_t)kc * 6 + wt) * NB + b) * NR + r];
        rel[((size_t)wt * NB + b) * NR + r] = 1.f / (1.f + expf(-a));
    }
}

// ================= hop attention: 32 blocks (w,b), 3 waves (one per t) =================
__global__ __launch_bounds__(192) void hop_kernel(
    const float* __restrict__ qe, const float* __restrict__ hopW,
    const float* __restrict__ hopB, float* __restrict__ hop)
{
    int wb = blockIdx.x;
    int w = wb / NB, b = wb % NB;
    int t = threadIdx.x / 64, l = threadIdx.x % 64;
    __shared__ float s_logit[4];
    float a = 0.f;
    for (int h = l; h < NH; h += 64) a += qe[b * NH + h] * hopW[((size_t)w * NH + h) * NSTEPS + t];
    for (int off = 32; off; off >>= 1) a += __shfl_down(a, off, 64);
    if (l == 0) s_logit[t] = a + hopB[w * NSTEPS + t];
    __syncthreads();
    if (threadIdx.x == 0) {
        float mx = fmaxf(s_logit[0], fmaxf(s_logit[1], s_logit[2]));
        float e0 = expf(s_logit[0] - mx), e1 = expf(s_logit[1] - mx), e2 = expf(s_logit[2] - mx);
        float inv = 1.f / (e0 + e1 + e2);
        hop[wb * NSTEPS + 0] = e0 * inv;
        hop[wb * NSTEPS + 1] = e1 * inv;
        hop[wb * NSTEPS + 2] = e2 * inv;
    }
}

// ================= gen0 frontier from one-hot heads =================
__global__ void head_kernel(const float* __restrict__ heads, int* __restrict__ keys0,
                            float* __restrict__ vals0, u32* __restrict__ bm0)
{
    size_t N4 = (size_t)NB * NE / 4;
    const float4* h4 = (const float4*)heads;
    for (size_t i = (size_t)blockIdx.x * blockDim.x + threadIdx.x; i < N4;
         i += (size_t)gridDim.x * blockDim.x) {
        float4 v = h4[i];
        float c[4] = { v.x, v.y, v.z, v.w };
#pragma unroll
        for (int k = 0; k < 4; ++k) {
            if (c[k] != 0.0f) {
                size_t idx = i * 4 + k;
                int b = (int)(idx / NE);
                int e = (int)(idx % NE);
                int s = fhash(e);
                keys0[(size_t)b * HSZ + s] = e + 1;
                vals0[(size_t)b * HSZ + s] = 1.0f;
                vals0[(size_t)(NB + b) * HSZ + s] = 1.0f;
                atomicOr(&bm0[(size_t)b * BMW + (e >> 5)], 1u << (e & 31));
            }
        }
    }
}

// ================= propagate gen t -> gen t+1 (both ways, shared keys) =================
// grid: b(16) x chunk(40) = 640 blocks
__global__ __launch_bounds__(256) void prop_kernel(
    const int* __restrict__ triples,
    const u32* __restrict__ bmIn, const int* __restrict__ keysIn, const float* __restrict__ valsIn,
    u32* __restrict__ bmOut, int* __restrict__ keysOut, float* __restrict__ valsOut,
    const float* __restrict__ rel, int t)
{
    __shared__ u32 s_bm[BMW];
    int b = blockIdx.x / PCHUNK;
    int c = blockIdx.x % PCHUNK;
    const u32* g = bmIn + (size_t)b * BMW;
    for (int k = threadIdx.x; k < BMW; k += 256) s_bm[k] = g[k];
    __syncthreads();

    const int*   kin  = keysIn  + (size_t)b * HSZ;
    const float* v0in = valsIn  + (size_t)b * HSZ;
    const float* v1in = valsIn  + (size_t)(NB + b) * HSZ;
    const float* r0 = rel + ((size_t)(0 * NSTEPS + t) * NB + b) * NR;
    const float* r1 = rel + ((size_t)(1 * NSTEPS + t) * NB + b) * NR;
    int*   kout  = keysOut + (size_t)b * HSZ;
    float* v0out = valsOut + (size_t)b * HSZ;
    float* v1out = valsOut + (size_t)(NB + b) * HSZ;
    u32*   bmo   = bmOut + (size_t)b * BMW;

    const int4* tp = (const int4*)(triples + (size_t)b * NT * 3);
    const int QPC = (NT / 4) / PCHUNK;     // 1250 quads per chunk
    int qend = (c + 1) * QPC;
    for (int q = c * QPC + threadIdx.x; q < qend; q += 256) {
        int4 x = tp[q * 3 + 0];
        int4 y = tp[q * 3 + 1];
        int4 z = tp[q * 3 + 2];
        int su[4] = { x.x, x.w, y.z, z.y };
        int re[4] = { x.y, y.x, y.w, z.z };
        int ob[4] = { x.z, y.y, z.x, z.w };
#pragma unroll
        for (int k = 0; k < 4; ++k) {
            int sub = su[k];
            if ((s_bm[sub >> 5] >> (sub & 31)) & 1u) {
                int s = fhash(sub);
                float v0 = 0.f, v1 = 0.f;
                bool found = false;
                for (int p = 0; p < HSZ; ++p) {
                    int kk = kin[s];
                    if (kk == 0) break;
                    if (kk == sub + 1) {
                        v0 = fminf(v0in[s], 1.0f);
                        v1 = fminf(v1in[s], 1.0f);
                        found = true;
                        break;
                    }
                    s = (s + 1) & (HSZ - 1);
                }
                if (found) {
                    float c0 = v0 * r0[re[k]];
                    float c1 = v1 * r1[re[k]];
                    int e = ob[k];
                    int s2 = fhash(e);
                    for (int p = 0; p < HSZ; ++p) {
                        int old = atomicCAS(&kout[s2], 0, e + 1);
                        if (old == 0 || old == e + 1) {
                            atomicAdd(&v0out[s2], c0);
                            atomicAdd(&v1out[s2], c1);
                            if (old == 0) atomicOr(&bmo[e >> 5], 1u << (e & 31));
                            break;
                        }
                        s2 = (s2 + 1) & (HSZ - 1);
                    }
                }
            }
        }
    }
}

// ================= final: hop-weighted accumulate gens 1..3, product of ways =================
__global__ __launch_bounds__(256) void final_kernel(
    const int* __restrict__ keysG, const float* __restrict__ valsG,
    const float* __restrict__ hop, float* __restrict__ out)
{
    __shared__ int s_k[AHSZ];
    __shared__ float s_v0[AHSZ];
    __shared__ float s_v1[AHSZ];
    int b = blockIdx.x;
    for (int i = threadIdx.x; i < AHSZ; i += 256) { s_k[i] = 0; s_v0[i] = 0.f; s_v1[i] = 0.f; }
    __syncthreads();
    for (int gen = 1; gen <= 3; ++gen) {
        const int* kg = keysG + ((size_t)gen * NB + b) * HSZ;
        const float* vg = valsG + (size_t)gen * NWAYS * NB * HSZ;
        const float* v0 = vg + (size_t)b * HSZ;
        const float* v1 = vg + (size_t)(NB + b) * HSZ;
        float h0 = hop[(0 * NB + b) * NSTEPS + (gen - 1)];
        float h1 = hop[(1 * NB + b) * NSTEPS + (gen - 1)];
        for (int i = threadIdx.x; i < HSZ; i += 256) {
            int key = kg[i];
            if (key == 0) continue;
            float a0 = h0 * fminf(v0[i], 1.0f);
            float a1 = h1 * fminf(v1[i], 1.0f);
            int s = ahash(key - 1);
            for (int p = 0; p < AHSZ; ++p) {
                int old = atomicCAS(&s_k[s], 0, key);
                if (old == 0 || old == key) {
                    atomicAdd(&s_v0[s], a0);
                    atomicAdd(&s_v1[s], a1);
                    break;
                }
                s = (s + 1) & (AHSZ - 1);
            }
        }
    }
    __syncthreads();
    for (int i = threadIdx.x; i < AHSZ; i += 256) {
        int key = s_k[i];
        if (key) out[(size_t)b * NE + (key - 1)] = s_v0[i] * s_v1[i];
    }
}

extern "C" void kernel_launch(void* const* d_in, const int* in_sizes, int n_in,
                              void* d_out, int out_size, void* d_ws, size_t ws_size,
                              hipStream_t stream)
{
    const float* heads  = (const float*)d_in[0];
    const float* qe     = (const float*)d_in[1];
    const float* qwh    = (const float*)d_in[2];
    const float* mask   = (const float*)d_in[3];
    const float* stepW  = (const float*)d_in[4];
    const float* stepB  = (const float*)d_in[5];
    const float* relW   = (const float*)d_in[6];
    const float* relB   = (const float*)d_in[7];
    const float* hopW   = (const float*)d_in[8];
    const float* hopB   = (const float*)d_in[9];
    const int*   triples = (const int*)d_in[10];
    float* out = (float*)d_out;

    // workspace: [keysG 4][valsG 4x2][bmG 4][rel][hop][part][ctx][part_r]
    int*   keysG = (int*)d_ws;                                   // 4*16*2048
    float* valsG = (float*)(keysG + 4 * NB * HSZ);               // 4*2*16*2048
    u32*   bmG   = (u32*)(valsG + 4 * NWAYS * NB * HSZ);         // 4*16*6272
    float* rel   = (float*)(bmG + 4 * (size_t)NB * BMW);         // 96*500
    float* hop   = rel + (size_t)NWAYS * NSTEPS * NB * NR;       // 96
    float* part  = hop + NWAYS * NB * NSTEPS;                    // 4*6*16*768
    float* ctx   = part + (size_t)4 * 6 * NB * NH;               // 6*16*768
    float* part_r = ctx + (size_t)6 * NB * NH;                   // 12*6*16*500

    size_t zero_bytes = (char*)rel - (char*)d_ws;                // keys+vals+bm, ~3.1 MB
    hipMemsetAsync(d_ws, 0, zero_bytes, stream);
    hipMemsetAsync(d_out, 0, (size_t)NB * NE * sizeof(float), stream);

    cq_part_kernel<<<288, 256, 0, stream>>>(qe, stepW, part);
    hop_kernel<<<NWAYS * NB, 192, 0, stream>>>(qe, hopW, hopB, hop);
    head_kernel<<<2048, 256, 0, stream>>>(heads, keysG, valsG, bmG);
    attn_kernel<<<96, 256, 0, stream>>>(part, stepB, qwh, mask, ctx);
    rel_part_kernel<<<192, 256, 0, stream>>>(ctx, relW, part_r);
    rel_reduce_kernel<<<96, 256, 0, stream>>>(part_r, relB, rel);

    for (int t = 0; t < NSTEPS; ++t) {
        prop_kernel<<<NB * PCHUNK, 256, 0, stream>>>(
            triples,
            bmG + (size_t)t * NB * BMW,
            keysG + (size_t)t * NB * HSZ,
            valsG + (size_t)t * NWAYS * NB * HSZ,
            bmG + (size_t)(t + 1) * NB * BMW,
            keysG + (size_t)(t + 1) * NB * HSZ,
            valsG + (size_t)(t + 1) * NWAYS * NB * HSZ,
            rel, t);
    }

    final_kernel<<<NB, 256, 0, stream>>>(keysG, valsG, hop, out);
}